// Round 10
// baseline (271.671 us; speedup 1.0000x reference)
//
#include <hip/hip_runtime.h>

#define PTOT   1048576
#define NRAYS  8192
#define THRESH 1e-4f
#define ECAP   PTOT     // per-expert entry region; provable bound (e0!=e1 => <=1 entry/expert/point)
#define WPTS   512      // scan window: 4 pairs x 128 points (real max ray len ~176)

typedef float F2 __attribute__((ext_vector_type(2)));

__device__ __forceinline__ F2 f2splat(float s){ F2 r; r.x = s; r.y = s; return r; }
__device__ __forceinline__ F2 f2fma(F2 a, float b, F2 c){
    return __builtin_elementwise_fma(a, f2splat(b), c);
}
__device__ __forceinline__ float raw2alpha_f(float d){
    // 1 - exp(-softplus(d - 4) * 0.5) == 1 - (1 + e^(d-4))^(-1/2)
    return 1.0f - rsqrtf(1.0f + __expf(d - 4.0f));
}

// ---------------- kernel 0: ray segment boundaries ----------------
__global__ __launch_bounds__(256) void k_rayoff(const int* __restrict__ ray_id,
                                                int* __restrict__ ray_off)
{
    int p = blockIdx.x*256 + threadIdx.x;
    int r = ray_id[p];
    int prev = (p == 0) ? -1 : ray_id[p-1];
    if (r != prev) for (int rr = prev+1; rr <= r; ++rr) ray_off[rr] = p;
    if (p == PTOT-1) for (int rr = r+1; rr <= NRAYS; ++rr) ray_off[rr] = PTOT;
}

// -------- kernel 1: FUSED density MLP + gate + transmittance scan + entry fill ----------
// Wave = ray. Density/gate computed in registers (no alpha0/g0a/eea arrays, no vdirs
// gather in the gate: viewdir is wave-uniform -> per-expert scalar offset). Scan and
// ballot-ranked fill run immediately on register data. Saves 24MB of round-trip traffic,
// one kernel launch, and a full duplicated gate/ballot pass vs the R9 split.
// Window loop is BLOCK-UNIFORM (shared atomicMax of per-ray window counts) so the
// __syncthreads inside is safe; register arrays are only indexed via #pragma unroll
// constants (avoids scratch).
__global__ __launch_bounds__(256) void k_pointscan(
    const float* __restrict__ pts, const float* __restrict__ vdirs,
    const float* __restrict__ Wd1, const float* __restrict__ bd1,
    const float* __restrict__ Wd2, const float* __restrict__ Wg,
    const int* __restrict__ ray_off,
    unsigned char* __restrict__ keep, int* __restrict__ cntA,
    int2* __restrict__ ent)
{
    __shared__ float4 WD4[128];   // {Wd1[0][i], Wd1[1][i], Wd1[2][i], bd1[i]}
    __shared__ float  WD2s[128];
    __shared__ float  WGs[8][6];  // Wg[k][e] flat = k*8+e -> WGs[e][k]
    __shared__ int wcs[4][8];
    __shared__ int wb[4][8];
    __shared__ int sMaxW;
    int t = threadIdx.x, lane = t & 63, w = t >> 6;
    unsigned long long lt = (1ull << lane) - 1ull;
    if (t < 128){
        WD4[t] = make_float4(Wd1[t], Wd1[128+t], Wd1[256+t], bd1[t]);
        WD2s[t] = Wd2[t];
    }
    if (t < 48) WGs[t & 7][t >> 3] = Wg[t];
    if (t == 0) sMaxW = 0;
    __syncthreads();

    int wid = blockIdx.x*4 + w;                      // wave = ray
    int s = ray_off[wid], e = ray_off[wid+1];
    // wave-uniform viewdir -> per-expert gate offset
    float vx = vdirs[3*wid], vy = vdirs[3*wid+1], vz = vdirs[3*wid+2];
    float goff[8];
    #pragma unroll
    for (int x=0;x<8;x++) goff[x] = vx*WGs[x][3] + vy*WGs[x][4] + vz*WGs[x][5];

    int nw = (e > s) ? (e - s + WPTS - 1) / WPTS : 0;
    if (lane == 0) atomicMax(&sMaxW, nw);
    __syncthreads();
    int wmax = sMaxW;

    float carry = 1.f;
    for (int win = 0; win < wmax; ++win){
        int wbase = s + win*WPTS;
        bool active = (wbase < e);

        F2 av[4], gv[4]; int2 ev[4];   // per-pair alpha / gate / expert ids (static idx only)
        int kbits = 0;
        int c[8];
        #pragma unroll
        for (int x=0;x<8;x++) c[x]=0;

        // ---- compute phase: density MLP + gate per 128-point pair-group ----
        #pragma unroll
        for (int pp=0; pp<4; ++pp){
            av[pp] = f2splat(0.f); gv[pp] = f2splat(0.f); ev[pp] = make_int2(0,0);
            int pbase = wbase + pp*128;
            if (active && pbase < e){                // wave-uniform guard
                int p0 = pbase + lane, p1 = pbase + 64 + lane;
                bool in0 = p0 < e, in1 = p1 < e;
                F2 px = (F2){ in0 ? pts[3*p0]   : 0.f, in1 ? pts[3*p1]   : 0.f };
                F2 py = (F2){ in0 ? pts[3*p0+1] : 0.f, in1 ? pts[3*p1+1] : 0.f };
                F2 pz = (F2){ in0 ? pts[3*p0+2] : 0.f, in1 ? pts[3*p1+2] : 0.f };
                F2 dens = f2splat(0.f);
                #pragma unroll 2
                for (int i=0;i<128;i++){
                    float4 wv = WD4[i]; float w2 = WD2s[i];
                    F2 h = f2fma(px, wv.x, f2fma(py, wv.y, f2fma(pz, wv.z, f2splat(wv.w))));
                    h = __builtin_elementwise_max(h, f2splat(0.f));
                    dens = f2fma(h, w2, dens);
                }
                float a0 = raw2alpha_f(dens.x); a0 = (a0 > THRESH) ? a0 : 0.f; if (!in0) a0 = 0.f;
                float a1 = raw2alpha_f(dens.y); a1 = (a1 > THRESH) ? a1 : 0.f; if (!in1) a1 = 0.f;
                av[pp] = (F2){a0, a1};
                // gate: top-2 of softmax over 8 experts
                float m0a=-3.0e38f, m1a=-3.0e38f, m0b=-3.0e38f, m1b=-3.0e38f;
                int i0a=0, i1a=0, i0b=0, i1b=0;
                for (int x=0;x<8;x++){
                    float w0=WGs[x][0], w1=WGs[x][1], w2g=WGs[x][2];
                    F2 l = f2fma(px, w0, f2fma(py, w1,
                           __builtin_elementwise_fma(pz, f2splat(w2g), f2splat(goff[x]))));
                    float lx = l.x, ly = l.y;
                    if (lx > m0a){ m1a=m0a; i1a=i0a; m0a=lx; i0a=x; }
                    else if (lx > m1a){ m1a=lx; i1a=x; }
                    if (ly > m0b){ m1b=m0b; i1b=i0b; m0b=ly; i0b=x; }
                    else if (ly > m1b){ m1b=ly; i1b=x; }
                }
                float ga = __fdividef(1.0f, 1.0f + __expf(m1a-m0a));
                float gb = __fdividef(1.0f, 1.0f + __expf(m1b-m0b));
                gv[pp] = (F2){ga, gb};
                ev[pp] = make_int2(i0a | (i1a << 8), i0b | (i1b << 8));
            }
        }

        // ---- scan + count phase (point order: pp, half, lane) ----
        #pragma unroll
        for (int pp=0; pp<4; ++pp){
            #pragma unroll
            for (int half=0; half<2; ++half){
                int p = wbase + pp*128 + half*64 + lane;
                bool in = active && (p < e);
                float a = half ? av[pp].y : av[pp].x;      // 0 for invalid lanes
                float incl = 1.f - a;
                #pragma unroll
                for (int d=1; d<64; d<<=1){ float tt = __shfl_up(incl, d); if (lane >= d) incl *= tt; }
                float excl = __shfl_up(incl, 1); if (lane == 0) excl = 1.f;
                float w0v = a * carry * excl;
                int k = (in && w0v > THRESH) ? 1 : 0;
                if (in) keep[p] = (unsigned char)k;
                kbits |= k << (2*pp + half);
                int eepk = half ? ev[pp].y : ev[pp].x;
                int e0 = eepk & 255, e1 = (eepk >> 8) & 255;
                #pragma unroll
                for (int x=0;x<8;x++){
                    unsigned long long m0 = __ballot(k && e0==x);
                    unsigned long long m1 = __ballot(k && e1==x);
                    c[x] += __popcll(m0) + __popcll(m1);
                }
                carry *= __shfl(incl, 63);
            }
        }

        // ---- block-level reservation ----
        if (lane == 0){
            #pragma unroll
            for (int x=0;x<8;x++) wcs[w][x] = c[x];
        }
        __syncthreads();
        if (t < 8){
            int tot = wcs[0][t]+wcs[1][t]+wcs[2][t]+wcs[3][t];
            int b = tot ? atomicAdd(&cntA[t], tot) : 0;
            wb[0][t] = b; b += wcs[0][t];
            wb[1][t] = b; b += wcs[1][t];
            wb[2][t] = b; b += wcs[2][t];
            wb[3][t] = b;
        }
        __syncthreads();
        int cur[8];
        #pragma unroll
        for (int x=0;x<8;x++) cur[x] = x*ECAP + wb[w][x];

        // ---- fill phase (same traversal order as count; register data) ----
        #pragma unroll
        for (int pp=0; pp<4; ++pp){
            #pragma unroll
            for (int half=0; half<2; ++half){
                int p = wbase + pp*128 + half*64 + lane;
                int k = (kbits >> (2*pp + half)) & 1;
                int eepk = half ? ev[pp].y : ev[pp].x;
                float g0 = half ? gv[pp].y : gv[pp].x;
                int e0 = eepk & 255, e1 = (eepk >> 8) & 255;
                #pragma unroll
                for (int x=0;x<8;x++){
                    unsigned long long m0 = __ballot(k && e0==x);
                    unsigned long long m1 = __ballot(k && e1==x);
                    if (k && e0==x)
                        ent[cur[x] + __popcll(m0 & lt)] = make_int2(p, __float_as_int(g0));
                    if (k && e1==x)
                        ent[cur[x] + __popcll(m0) + __popcll(m1 & lt)] =
                            make_int2(p | (1 << 30), __float_as_int(1.0f - g0));
                    cur[x] += __popcll(m0) + __popcll(m1);
                }
            }
        }
        // next window: wcs rewrite races are impossible (each wave writes only its own
        // row, and all waves copied wb into registers before their fill phase)
    }
}

// ---------------- kernel 2: expert MLPs (exact R9/R6 core; fixed-region segments) --------
// Best measured config (R9: 82us, VALU 59-61, occ 29, FETCH 42GB): 256 thr, 4 F2 pairs,
// chunk 2048, zero-dead padded-prefix grid (1032 blocks), LDS float4 weights, viewdirs
// re-gathered via ray_id[p] (L2-hot).
// NOTE: MFMA slower (99 vs 91). s_load weights slower (127, R1). Packed 32B entries no
// help (92.6, R2). pk_fma not double-rate on CDNA4 (97, R3). 16 e/t: occupancy collapse
// (128, R4) and VGPR-restructure regression (88.5, R7). 128-thr blocks: no help (R5/R7).
__global__ __launch_bounds__(256) void k_expert(
    const int2* __restrict__ ent, const int* __restrict__ cntA,
    const float* __restrict__ pts, const int* __restrict__ ray_id,
    const float* __restrict__ vdirs,
    const float* __restrict__ We1, const float* __restrict__ be1,
    const float* __restrict__ Wrgb, const float* __restrict__ Walpha,
    float4* __restrict__ res)
{
    // padded-prefix chunk search over per-expert counts (uniform scalar)
    int k = blockIdx.x;
    int e = -1, n = 0, base = 0;
    int acc = 0;
    #pragma unroll
    for (int i=0;i<8;i++){
        int c  = cntA[i];                    // <= ECAP by construction
        int ch = (c + 2047) >> 11;           // 2048-entry chunks this expert needs
        if (e < 0 && k < acc + ch){ e = i; n = c; base = (k - acc) << 11; }
        acc += ch;
    }
    if (e < 0) return;                        // beyond total chunk count (tail guard)

    __shared__ float4 WA[128];   // We1[e][0..3][i]
    __shared__ float4 WB[128];   // We1[e][4][i], We1[e][5][i], be1[e][i], Walpha[e][i]
    __shared__ float4 WC[128];   // Wrgb[e][i][0..2], 0
    int t = threadIdx.x;
    if (t < 128){
        const float* w = We1 + e*768;
        WA[t] = make_float4(w[t], w[128+t], w[256+t], w[384+t]);
        WB[t] = make_float4(w[512+t], w[640+t], be1[e*128+t], Walpha[e*128+t]);
        const float* wr = Wrgb + e*384 + 3*t;
        WC[t] = make_float4(wr[0], wr[1], wr[2], 0.f);
    }
    __syncthreads();
    const int2* eb = ent + (size_t)e * ECAP;

    F2 x0[4],x1[4],x2[4],x3[4],x4[4],x5[4];
    F2 ar[4],ag[4],ab[4],aa[4];
    #pragma unroll
    for (int pr=0;pr<4;pr++){
        int idx0 = base + t + (2*pr)*256, idx1 = idx0 + 256;
        int2 r0 = (idx0 < n) ? eb[idx0] : make_int2(0,0);
        int2 r1 = (idx1 < n) ? eb[idx1] : make_int2(0,0);
        int p0 = r0.x & 0x0FFFFFFF, p1 = r1.x & 0x0FFFFFFF;
        int ra = ray_id[p0], rb = ray_id[p1];
        x0[pr] = (F2){pts[3*p0],   pts[3*p1]};
        x1[pr] = (F2){pts[3*p0+1], pts[3*p1+1]};
        x2[pr] = (F2){pts[3*p0+2], pts[3*p1+2]};
        x3[pr] = (F2){vdirs[3*ra],   vdirs[3*rb]};
        x4[pr] = (F2){vdirs[3*ra+1], vdirs[3*rb+1]};
        x5[pr] = (F2){vdirs[3*ra+2], vdirs[3*rb+2]};
        ar[pr] = f2splat(0.f); ag[pr] = f2splat(0.f);
        ab[pr] = f2splat(0.f); aa[pr] = f2splat(0.f);
    }
    #pragma unroll 2
    for (int i=0;i<128;i++){
        float4 wa = WA[i], wb = WB[i], wc = WC[i];
        #pragma unroll
        for (int pr=0;pr<4;pr++){
            F2 h = f2fma(x0[pr],wa.x, f2fma(x1[pr],wa.y, f2fma(x2[pr],wa.z,
                   f2fma(x3[pr],wa.w, f2fma(x4[pr],wb.x, f2fma(x5[pr],wb.y,
                   f2splat(wb.z)))))));
            h = __builtin_elementwise_max(h, f2splat(0.f));
            ar[pr] = f2fma(h, wc.x, ar[pr]);
            ag[pr] = f2fma(h, wc.y, ag[pr]);
            ab[pr] = f2fma(h, wc.z, ab[pr]);
            aa[pr] = f2fma(h, wb.w, aa[pr]);
        }
    }
    #pragma unroll
    for (int pr=0;pr<4;pr++){
        #pragma unroll
        for (int sel=0; sel<2; sel++){
            int idx = base + t + (2*pr+sel)*256;
            if (idx < n){
                int2 rec = eb[idx];                 // reload g/pid (keeps loop VGPRs low)
                float vr = sel ? ar[pr].y : ar[pr].x;
                float vg = sel ? ag[pr].y : ag[pr].x;
                float vb = sel ? ab[pr].y : ab[pr].x;
                float va = sel ? aa[pr].y : aa[pr].x;
                float sr = __fdividef(1.0f, 1.0f + __expf(-vr));
                float sg = __fdividef(1.0f, 1.0f + __expf(-vg));
                float sb = __fdividef(1.0f, 1.0f + __expf(-vb));
                float a  = raw2alpha_f(va);
                float g  = __int_as_float(rec.y);
                int pp   = rec.x & 0x0FFFFFFF;
                int slot = ((unsigned)rec.x) >> 30;
                res[2*(size_t)pp + slot] = make_float4(g*sr, g*sg, g*sb, g*a);
            }
        }
    }
}

// ---------------- kernel 3: final per-ray composite ----------------
__global__ __launch_bounds__(256) void k_scan1(const float4* __restrict__ res,
                                               const unsigned char* __restrict__ keep,
                                               const int* __restrict__ ray_off,
                                               const float* __restrict__ bg,
                                               float* __restrict__ out)
{
    int wid  = (blockIdx.x*blockDim.x + threadIdx.x) >> 6;   // wave = ray
    int lane = threadIdx.x & 63;
    if (wid >= NRAYS) return;
    int s = ray_off[wid], e = ray_off[wid+1];
    float carry = 1.f;
    float accx = 0.f, accy = 0.f, accz = 0.f;
    for (int c = s; c < e; c += 64){
        int p = c + lane;
        float4 v = make_float4(0.f,0.f,0.f,0.f);
        if (p < e && keep[p]){
            float4 v0 = res[2*(size_t)p];
            float4 v1 = res[2*(size_t)p + 1];
            v = make_float4(v0.x+v1.x, v0.y+v1.y, v0.z+v1.z, v0.w+v1.w);
        }
        float a = v.w;
        float incl = 1.f - a;
        #pragma unroll
        for (int d=1; d<64; d<<=1){ float tt = __shfl_up(incl, d); if (lane >= d) incl *= tt; }
        float excl = __shfl_up(incl, 1); if (lane == 0) excl = 1.f;
        float w = a * carry * excl;
        accx = fmaf(w, v.x, accx);
        accy = fmaf(w, v.y, accy);
        accz = fmaf(w, v.z, accz);
        carry *= __shfl(incl, 63);
    }
    #pragma unroll
    for (int d=32; d; d>>=1){
        accx += __shfl_xor(accx, d);
        accy += __shfl_xor(accy, d);
        accz += __shfl_xor(accz, d);
    }
    if (lane == 0){
        out[3*wid+0] = accx + carry*bg[0];
        out[3*wid+1] = accy + carry*bg[1];
        out[3*wid+2] = accz + carry*bg[2];
    }
}

extern "C" void kernel_launch(void* const* d_in, const int* in_sizes, int n_in,
                              void* d_out, int out_size, void* d_ws, size_t ws_size,
                              hipStream_t stream)
{
    const float* pts    = (const float*)d_in[0];
    const float* vdirs  = (const float*)d_in[1];
    const float* bg     = (const float*)d_in[2];
    const float* Wd1    = (const float*)d_in[3];
    const float* bd1    = (const float*)d_in[4];
    const float* Wd2    = (const float*)d_in[5];
    const float* Wg     = (const float*)d_in[6];
    const float* We1    = (const float*)d_in[7];
    const float* be1    = (const float*)d_in[8];
    const float* Wrgb   = (const float*)d_in[9];
    const float* Walpha = (const float*)d_in[10];
    const int*   ray_id = (const int*)d_in[11];
    float* out = (float*)d_out;

    // Workspace (~97.2MB, R9-proven footprint):
    //   [keep 1MB][ray_off][cntA][res 32MB+32B][ent 64MB]
    char* ws = (char*)d_ws;
    size_t off = 0;
    unsigned char* keep  = (unsigned char*)(ws + off); off += (size_t)PTOT;   // 1MB
    int*   ray_off       = (int*)  (ws + off); off += 33024;                  // 8193+ ints
    int*   cntA          = (int*)  (ws + off); off += 256;
    off = (off + 255) & ~(size_t)255;
    float4* res          = (float4*)(ws + off); off += ((size_t)2*PTOT + 2)*16; // 32MB
    off = (off + 255) & ~(size_t)255;
    int2*  ent           = (int2*) (ws + off); off += (size_t)8*ECAP*8;         // 64MB

    hipMemsetAsync(cntA, 0, 256, stream);

    k_rayoff   <<<PTOT/256, 256, 0, stream>>>(ray_id, ray_off);
    k_pointscan<<<NRAYS/4, 256, 0, stream>>>(pts, vdirs, Wd1, bd1, Wd2, Wg,
                                             ray_off, keep, cntA, ent);
    // grid = max total chunks: Sum_e ceil(n_e/2048) <= 2*PTOT/2048 + 8 = 1032
    k_expert   <<<1032, 256, 0, stream>>>(ent, cntA, pts, ray_id, vdirs,
                                          We1, be1, Wrgb, Walpha, res);
    k_scan1    <<<NRAYS*64/256, 256, 0, stream>>>(res, keep, ray_off, bg, out);
}

// Round 11
// 222.405 us; speedup vs baseline: 1.2215x; 1.2215x over previous
//
#include <hip/hip_runtime.h>

#define PTOT   1048576
#define NRAYS  8192
#define THRESH 1e-4f
#define ECAP   PTOT     // per-expert entry region; provable bound (e0!=e1 => <=1 entry/expert/point)

typedef float F2 __attribute__((ext_vector_type(2)));

__device__ __forceinline__ F2 f2splat(float s){ F2 r; r.x = s; r.y = s; return r; }
__device__ __forceinline__ F2 f2fma(F2 a, float b, F2 c){
    return __builtin_elementwise_fma(a, f2splat(b), c);
}
__device__ __forceinline__ float raw2alpha_f(float d){
    // 1 - exp(-softplus(d - 4) * 0.5) == 1 - (1 + e^(d-4))^(-1/2)
    return 1.0f - rsqrtf(1.0f + __expf(d - 4.0f));
}

// ---------------- kernel 1: density alpha + gate + ray_off (+aux block) ----------------
// Blocks 0..1023: 1024 pts each (2 F2 pairs/thread), as in R9 (best measured).
// Block 1024 (aux): zeroes cntA (replaces the hipMemsetAsync dispatch, ~-10us launch
// overhead) and writes the transposed WA table for k_expert's scalar weight path.
__global__ __launch_bounds__(256) void k_point(
    const float* __restrict__ pts, const float* __restrict__ vdirs,
    const int* __restrict__ ray_id,
    const float* __restrict__ Wd1, const float* __restrict__ bd1,
    const float* __restrict__ Wd2, const float* __restrict__ Wg,
    const float* __restrict__ We1,
    float* __restrict__ alpha0, float* __restrict__ g0a, int* __restrict__ eea,
    int* __restrict__ ray_off, int* __restrict__ cntA, float4* __restrict__ WtA)
{
    if (blockIdx.x >= 1024){                  // aux block (uniform branch, no barriers)
        int tt = threadIdx.x;
        if (tt < 8) cntA[tt] = 0;
        for (int j = tt; j < 1024; j += 256){ // WtA[e*128+i] = {We1[e][0..3][i]}
            int ee = j >> 7, ii = j & 127;
            const float* w = We1 + ee*768;
            WtA[j] = make_float4(w[ii], w[128+ii], w[256+ii], w[384+ii]);
        }
        return;
    }

    __shared__ float4 WD4[128];   // {Wd1[0][i], Wd1[1][i], Wd1[2][i], bd1[i]}
    __shared__ float  WD2s[128];
    __shared__ float  WGs[8][6];
    int t = threadIdx.x;
    if (t < 128){
        WD4[t] = make_float4(Wd1[t], Wd1[128+t], Wd1[256+t], bd1[t]);
        WD2s[t] = Wd2[t];
    }
    if (t < 48) WGs[t & 7][t >> 3] = Wg[t];   // Wg[k][e] flat = k*8+e
    __syncthreads();

    int base = blockIdx.x * 1024 + t;         // 4 points/thread as 2 F2 pairs
    F2 px[2], py[2], pz[2], vx[2], vy[2], vz[2], dens[2];
    int rid0[2], rid1[2];
    #pragma unroll
    for (int q=0;q<2;q++){
        int p0 = base + (2*q)*256, p1 = p0 + 256;
        px[q] = (F2){pts[3*p0],   pts[3*p1]};
        py[q] = (F2){pts[3*p0+1], pts[3*p1+1]};
        pz[q] = (F2){pts[3*p0+2], pts[3*p1+2]};
        int r0 = ray_id[p0], r1 = ray_id[p1];
        rid0[q] = r0; rid1[q] = r1;
        vx[q] = (F2){vdirs[3*r0],   vdirs[3*r1]};
        vy[q] = (F2){vdirs[3*r0+1], vdirs[3*r1+1]};
        vz[q] = (F2){vdirs[3*r0+2], vdirs[3*r1+2]};
        dens[q] = f2splat(0.f);
    }
    // ray segment boundaries
    #pragma unroll
    for (int q=0;q<2;q++){
        int p0 = base + (2*q)*256, p1 = p0 + 256;
        int prev0 = (p0 == 0) ? -1 : ray_id[p0-1];
        if (prev0 != rid0[q]) for (int r=prev0+1; r<=rid0[q]; ++r) ray_off[r] = p0;
        int prev1 = ray_id[p1-1];
        if (prev1 != rid1[q]) for (int r=prev1+1; r<=rid1[q]; ++r) ray_off[r] = p1;
        if (p1 == PTOT-1) for (int r=rid1[q]+1; r<=NRAYS; ++r) ray_off[r] = PTOT;
    }
    #pragma unroll 2
    for (int i=0;i<128;i++){
        float4 w = WD4[i]; float w2 = WD2s[i];
        #pragma unroll
        for (int q=0;q<2;q++){
            F2 h = f2fma(px[q], w.x, f2fma(py[q], w.y, f2fma(pz[q], w.z, f2splat(w.w))));
            h = __builtin_elementwise_max(h, f2splat(0.f));
            dens[q] = f2fma(h, w2, dens[q]);
        }
    }
    #pragma unroll
    for (int q=0;q<2;q++){
        float a0 = raw2alpha_f(dens[q].x);
        float a1 = raw2alpha_f(dens[q].y);
        alpha0[base + (2*q)*256]   = (a0 > THRESH) ? a0 : 0.f;
        alpha0[base + (2*q+1)*256] = (a1 > THRESH) ? a1 : 0.f;
    }
    // gate: top-2 of softmax over 8 experts, renormalized
    float m0[4], m1[4]; int i0[4], i1[4];
    #pragma unroll
    for (int j=0;j<4;j++){ m0[j]=-3.0e38f; m1[j]=-3.0e38f; i0[j]=0; i1[j]=0; }
    for (int e=0;e<8;e++){
        float w0=WGs[e][0],w1=WGs[e][1],w2=WGs[e][2],w3=WGs[e][3],w4=WGs[e][4],w5=WGs[e][5];
        #pragma unroll
        for (int q=0;q<2;q++){
            F2 l = f2fma(px[q],w0, f2fma(py[q],w1, f2fma(pz[q],w2,
                   f2fma(vx[q],w3, f2fma(vy[q],w4,
                   __builtin_elementwise_fma(vz[q], f2splat(w5), f2splat(0.f)))))));
            int j0 = 2*q, j1 = 2*q+1;
            float lx = l.x, ly = l.y;
            if (lx > m0[j0]){ m1[j0]=m0[j0]; i1[j0]=i0[j0]; m0[j0]=lx; i0[j0]=e; }
            else if (lx > m1[j0]){ m1[j0]=lx; i1[j0]=e; }
            if (ly > m0[j1]){ m1[j1]=m0[j1]; i1[j1]=i0[j1]; m0[j1]=ly; i0[j1]=e; }
            else if (ly > m1[j1]){ m1[j1]=ly; i1[j1]=e; }
        }
    }
    #pragma unroll
    for (int j=0;j<4;j++){
        float g0 = __fdividef(1.0f, 1.0f + __expf(m1[j]-m0[j]));
        g0a[base + j*256] = g0;
        eea[base + j*256] = i0[j] | (i1[j] << 8);
    }
}

// -------- kernel 2: transmittance scan + keep + DIRECT entry fill (R9, unchanged) --------
__global__ __launch_bounds__(256) void k_scanfill(
    const float* __restrict__ alpha0, const int* __restrict__ eea,
    const float* __restrict__ g0a, const int* __restrict__ ray_off,
    unsigned char* __restrict__ keep, int* __restrict__ cntA,
    int2* __restrict__ ent)
{
    __shared__ int wcs[4][8];
    __shared__ int wb[4][8];
    int t = threadIdx.x, lane = t & 63, w = t >> 6;
    unsigned long long lt = (1ull << lane) - 1ull;
    int wid = blockIdx.x*4 + w;                      // wave = ray
    int s = ray_off[wid], e = ray_off[wid+1];

    // ---- pass 1: per-ray transmittance scan -> keep + per-expert counts ----
    int c[8];
    #pragma unroll
    for (int x=0;x<8;x++) c[x]=0;
    float carry = 1.f;
    for (int ch = s; ch < e; ch += 64){
        int p = ch + lane;
        bool in = p < e;
        float a = in ? alpha0[p] : 0.f;
        int  ee = in ? eea[p] : 0;
        float incl = 1.f - a;
        #pragma unroll
        for (int d=1; d<64; d<<=1){ float tt = __shfl_up(incl, d); if (lane >= d) incl *= tt; }
        float excl = __shfl_up(incl, 1); if (lane == 0) excl = 1.f;
        float w0 = a * carry * excl;
        int k = (in && w0 > THRESH) ? 1 : 0;
        if (in) keep[p] = (unsigned char)k;
        int e0 = ee & 255, e1 = (ee >> 8) & 255;
        #pragma unroll
        for (int x=0;x<8;x++){
            unsigned long long m0 = __ballot(k && e0==x);
            unsigned long long m1 = __ballot(k && e1==x);
            c[x] += __popcll(m0) + __popcll(m1);
        }
        carry *= __shfl(incl, 63);
    }
    if (lane == 0){
        #pragma unroll
        for (int x=0;x<8;x++) wcs[w][x] = c[x];
    }
    __syncthreads();
    // ---- block-level reservation: one atomic per expert ----
    if (t < 8){
        int tot = wcs[0][t]+wcs[1][t]+wcs[2][t]+wcs[3][t];
        int b = tot ? atomicAdd(&cntA[t], tot) : 0;
        wb[0][t] = b; b += wcs[0][t];
        wb[1][t] = b; b += wcs[1][t];
        wb[2][t] = b; b += wcs[2][t];
        wb[3][t] = b;
    }
    __syncthreads();
    int cur[8];
    #pragma unroll
    for (int x=0;x<8;x++) cur[x] = x*ECAP + wb[w][x];

    // ---- pass 2: re-ballot (hot reads) + ranked scatter into fixed regions ----
    for (int ch = s; ch < e; ch += 64){
        int p = ch + lane;
        bool in = p < e;
        int  k  = in ? keep[p] : 0;
        int  ee = in ? eea[p] : 0;
        float g0 = in ? g0a[p] : 0.f;
        int e0 = ee & 255, e1 = (ee >> 8) & 255;
        #pragma unroll
        for (int x=0;x<8;x++){
            unsigned long long m0 = __ballot(k && e0==x);
            unsigned long long m1 = __ballot(k && e1==x);
            if (k && e0==x)
                ent[cur[x] + __popcll(m0 & lt)] = make_int2(p, __float_as_int(g0));
            if (k && e1==x)
                ent[cur[x] + __popcll(m0) + __popcll(m1 & lt)] =
                    make_int2(p | (1 << 30), __float_as_int(1.0f - g0));
            cur[x] += __popcll(m0) + __popcll(m1);
        }
    }
}

// ---------------- kernel 3: expert MLPs (R9 core + hybrid scalar WA) ----------------
// LDS-pipe model (validated R6/R9: demand/VALU = 4x36/88 = 1.64 -> ceiling 61%;
// measured 59-61%): move ONE of the three per-iter ds_read_b128 to the SCALAR pipe —
// WA[i] as s_load_dwordx4 from the transposed WtA table (readfirstlane-forced SGPR
// bases). New ratio 4x24/88 = 1.09 -> VALU ceiling 92%. WB/WC stay in LDS; 4-pair
// ILP / 256-thr / chunk-2048 / zero-dead grid all unchanged (best measured).
// NOTE: MFMA slower (99 vs 91). PURE s_load weights slower (127, R1 — 2-pair ILP,
// all-scalar latency path; hybrid keeps both). pk_fma not double-rate (97, R3).
// 16 e/t: occupancy collapse (R4)/VGPR restructure (R7). 128-thr: no help (R5/R7).
__global__ __launch_bounds__(256) void k_expert(
    const int2* __restrict__ ent, const int* __restrict__ cntA,
    const float* __restrict__ pts, const int* __restrict__ ray_id,
    const float* __restrict__ vdirs,
    const float* __restrict__ We1, const float* __restrict__ be1,
    const float* __restrict__ Wrgb, const float* __restrict__ Walpha,
    const float4* __restrict__ WtA,
    float4* __restrict__ res)
{
    // padded-prefix chunk search over per-expert counts (uniform scalar)
    int k = blockIdx.x;
    int e = -1, n = 0, base = 0;
    int acc = 0;
    #pragma unroll
    for (int i=0;i<8;i++){
        int c  = cntA[i];                    // <= ECAP by construction
        int ch = (c + 2047) >> 11;           // 2048-entry chunks this expert needs
        if (e < 0 && k < acc + ch){ e = i; n = c; base = (k - acc) << 11; }
        acc += ch;
    }
    if (e < 0) return;                        // beyond total chunk count (tail guard)
    // force uniform values into SGPRs so WtA reads scalarize to s_load (HK trick)
    e    = __builtin_amdgcn_readfirstlane(e);
    n    = __builtin_amdgcn_readfirstlane(n);
    base = __builtin_amdgcn_readfirstlane(base);

    __shared__ float4 WB[128];   // We1[e][4][i], We1[e][5][i], be1[e][i], Walpha[e][i]
    __shared__ float4 WC[128];   // Wrgb[e][i][0..2], 0
    int t = threadIdx.x;
    if (t < 128){
        const float* w = We1 + e*768;
        WB[t] = make_float4(w[512+t], w[640+t], be1[e*128+t], Walpha[e*128+t]);
        const float* wr = Wrgb + e*384 + 3*t;
        WC[t] = make_float4(wr[0], wr[1], wr[2], 0.f);
    }
    __syncthreads();
    const int2* eb = ent + (size_t)e * ECAP;
    const float4* wA = WtA + (e << 7);       // uniform SGPR base

    F2 x0[4],x1[4],x2[4],x3[4],x4[4],x5[4];
    F2 ar[4],ag[4],ab[4],aa[4];
    #pragma unroll
    for (int pr=0;pr<4;pr++){
        int idx0 = base + t + (2*pr)*256, idx1 = idx0 + 256;
        int2 r0 = (idx0 < n) ? eb[idx0] : make_int2(0,0);
        int2 r1 = (idx1 < n) ? eb[idx1] : make_int2(0,0);
        int p0 = r0.x & 0x0FFFFFFF, p1 = r1.x & 0x0FFFFFFF;
        int ra = ray_id[p0], rb = ray_id[p1];
        x0[pr] = (F2){pts[3*p0],   pts[3*p1]};
        x1[pr] = (F2){pts[3*p0+1], pts[3*p1+1]};
        x2[pr] = (F2){pts[3*p0+2], pts[3*p1+2]};
        x3[pr] = (F2){vdirs[3*ra],   vdirs[3*rb]};
        x4[pr] = (F2){vdirs[3*ra+1], vdirs[3*rb+1]};
        x5[pr] = (F2){vdirs[3*ra+2], vdirs[3*rb+2]};
        ar[pr] = f2splat(0.f); ag[pr] = f2splat(0.f);
        ab[pr] = f2splat(0.f); aa[pr] = f2splat(0.f);
    }
    #pragma unroll 2
    for (int i=0;i<128;i++){
        float4 wa = wA[i];                    // scalar path (s_load_dwordx4, K$)
        float4 wb = WB[i], wc = WC[i];        // LDS path (2x ds_read_b128)
        #pragma unroll
        for (int pr=0;pr<4;pr++){
            F2 h = f2fma(x0[pr],wa.x, f2fma(x1[pr],wa.y, f2fma(x2[pr],wa.z,
                   f2fma(x3[pr],wa.w, f2fma(x4[pr],wb.x, f2fma(x5[pr],wb.y,
                   f2splat(wb.z)))))));
            h = __builtin_elementwise_max(h, f2splat(0.f));
            ar[pr] = f2fma(h, wc.x, ar[pr]);
            ag[pr] = f2fma(h, wc.y, ag[pr]);
            ab[pr] = f2fma(h, wc.z, ab[pr]);
            aa[pr] = f2fma(h, wb.w, aa[pr]);
        }
    }
    #pragma unroll
    for (int pr=0;pr<4;pr++){
        #pragma unroll
        for (int sel=0; sel<2; sel++){
            int idx = base + t + (2*pr+sel)*256;
            if (idx < n){
                int2 rec = eb[idx];                 // reload g/pid (keeps loop VGPRs low)
                float vr = sel ? ar[pr].y : ar[pr].x;
                float vg = sel ? ag[pr].y : ag[pr].x;
                float vb = sel ? ab[pr].y : ab[pr].x;
                float va = sel ? aa[pr].y : aa[pr].x;
                float sr = __fdividef(1.0f, 1.0f + __expf(-vr));
                float sg = __fdividef(1.0f, 1.0f + __expf(-vg));
                float sb = __fdividef(1.0f, 1.0f + __expf(-vb));
                float a  = raw2alpha_f(va);
                float g  = __int_as_float(rec.y);
                int pp   = rec.x & 0x0FFFFFFF;
                int slot = ((unsigned)rec.x) >> 30;
                res[2*(size_t)pp + slot] = make_float4(g*sr, g*sg, g*sb, g*a);
            }
        }
    }
}

// ---------------- kernel 4: final per-ray composite (unchanged) ----------------
__global__ __launch_bounds__(256) void k_scan1(const float4* __restrict__ res,
                                               const unsigned char* __restrict__ keep,
                                               const int* __restrict__ ray_off,
                                               const float* __restrict__ bg,
                                               float* __restrict__ out)
{
    int wid  = (blockIdx.x*blockDim.x + threadIdx.x) >> 6;   // wave = ray
    int lane = threadIdx.x & 63;
    if (wid >= NRAYS) return;
    int s = ray_off[wid], e = ray_off[wid+1];
    float carry = 1.f;
    float accx = 0.f, accy = 0.f, accz = 0.f;
    for (int c = s; c < e; c += 64){
        int p = c + lane;
        float4 v = make_float4(0.f,0.f,0.f,0.f);
        if (p < e && keep[p]){
            float4 v0 = res[2*(size_t)p];
            float4 v1 = res[2*(size_t)p + 1];
            v = make_float4(v0.x+v1.x, v0.y+v1.y, v0.z+v1.z, v0.w+v1.w);
        }
        float a = v.w;
        float incl = 1.f - a;
        #pragma unroll
        for (int d=1; d<64; d<<=1){ float tt = __shfl_up(incl, d); if (lane >= d) incl *= tt; }
        float excl = __shfl_up(incl, 1); if (lane == 0) excl = 1.f;
        float w = a * carry * excl;
        accx = fmaf(w, v.x, accx);
        accy = fmaf(w, v.y, accy);
        accz = fmaf(w, v.z, accz);
        carry *= __shfl(incl, 63);
    }
    #pragma unroll
    for (int d=32; d; d>>=1){
        accx += __shfl_xor(accx, d);
        accy += __shfl_xor(accy, d);
        accz += __shfl_xor(accz, d);
    }
    if (lane == 0){
        out[3*wid+0] = accx + carry*bg[0];
        out[3*wid+1] = accy + carry*bg[1];
        out[3*wid+2] = accz + carry*bg[2];
    }
}

extern "C" void kernel_launch(void* const* d_in, const int* in_sizes, int n_in,
                              void* d_out, int out_size, void* d_ws, size_t ws_size,
                              hipStream_t stream)
{
    const float* pts    = (const float*)d_in[0];
    const float* vdirs  = (const float*)d_in[1];
    const float* bg     = (const float*)d_in[2];
    const float* Wd1    = (const float*)d_in[3];
    const float* bd1    = (const float*)d_in[4];
    const float* Wd2    = (const float*)d_in[5];
    const float* Wg     = (const float*)d_in[6];
    const float* We1    = (const float*)d_in[7];
    const float* be1    = (const float*)d_in[8];
    const float* Wrgb   = (const float*)d_in[9];
    const float* Walpha = (const float*)d_in[10];
    const int*   ray_id = (const int*)d_in[11];
    float* out = (float*)d_out;

    // Workspace (~97.2MB + 16KB, R9-proven footprint):
    //   [keep 1MB][ray_off][cntA][WtA 16KB][A: alpha0|g0a|eea 12MB, res overlays][ent 64MB]
    char* ws = (char*)d_ws;
    size_t off = 0;
    unsigned char* keep  = (unsigned char*)(ws + off); off += (size_t)PTOT;   // 1MB
    int*   ray_off       = (int*)  (ws + off); off += 33024;                  // 8193+ ints
    int*   cntA          = (int*)  (ws + off); off += 256;
    off = (off + 255) & ~(size_t)255;
    float4* WtA          = (float4*)(ws + off); off += 8*128*16;              // 16KB
    off = (off + 255) & ~(size_t)255;
    size_t offA = off;
    float* alpha0        = (float*)(ws + offA);                                // 4MB
    float* g0a           = (float*)(ws + offA + (size_t)PTOT*4);               // 4MB
    int*   eea           = (int*)  (ws + offA + (size_t)PTOT*8);               // 4MB
    float4* res          = (float4*)(ws + offA);            // 32MB+32B, overlays A
    size_t resBytes      = ((size_t)2*PTOT + 2) * 16;
    size_t offE          = (offA + resBytes + 255) & ~(size_t)255;
    int2*  ent           = (int2*) (ws + offE);             // 8 * PTOT * 8B = 64MB

    // no memset dispatch: k_point's aux block zeroes cntA before k_scanfill runs
    k_point   <<<PTOT/1024 + 1, 256, 0, stream>>>(pts, vdirs, ray_id, Wd1, bd1, Wd2, Wg,
                                                  We1, alpha0, g0a, eea, ray_off,
                                                  cntA, WtA);
    k_scanfill<<<NRAYS/4, 256, 0, stream>>>(alpha0, eea, g0a, ray_off, keep, cntA, ent);
    // grid = max total chunks: Sum_e ceil(n_e/2048) <= 2*PTOT/2048 + 8 = 1032
    k_expert  <<<1032, 256, 0, stream>>>(ent, cntA, pts, ray_id, vdirs,
                                         We1, be1, Wrgb, Walpha, WtA, res);
    k_scan1   <<<NRAYS*64/256, 256, 0, stream>>>(res, keep, ray_off, bg, out);
}

// Round 13
// 220.116 us; speedup vs baseline: 1.2342x; 1.0104x over previous
//
#include <hip/hip_runtime.h>

#define PTOT   1048576
#define NRAYS  8192
#define THRESH 1e-4f
#define ECAP   PTOT     // per-expert entry region; provable bound (e0!=e1 => <=1 entry/expert/point)

typedef float F2 __attribute__((ext_vector_type(2)));

__device__ __forceinline__ F2 f2splat(float s){ F2 r; r.x = s; r.y = s; return r; }
__device__ __forceinline__ F2 f2fma(F2 a, float b, F2 c){
    return __builtin_elementwise_fma(a, f2splat(b), c);
}
__device__ __forceinline__ float raw2alpha_f(float d){
    // 1 - exp(-softplus(d - 4) * 0.5) == 1 - (1 + e^(d-4))^(-1/2)
    return 1.0f - rsqrtf(1.0f + __expf(d - 4.0f));
}

// ---------------- kernel 1: density alpha + gate + ray_off (+aux block) ----------------
// Blocks 0..1023: 1024 pts each (2 F2 pairs/thread) — R9 best-measured shape.
// Block 1024 (aux): zeroes cntA, replacing the hipMemsetAsync dispatch (R11: confirmed
// positive, ~-4us). Coop mega-kernel fusion REFUTED (R12: silent launch failure under
// graph capture); in-kernel point+scan fusion REFUTED (R10: 119us vs 77 split).
__global__ __launch_bounds__(256) void k_point(
    const float* __restrict__ pts, const float* __restrict__ vdirs,
    const int* __restrict__ ray_id,
    const float* __restrict__ Wd1, const float* __restrict__ bd1,
    const float* __restrict__ Wd2, const float* __restrict__ Wg,
    float* __restrict__ alpha0, float* __restrict__ g0a, int* __restrict__ eea,
    int* __restrict__ ray_off, int* __restrict__ cntA)
{
    if (blockIdx.x >= 1024){                  // aux block (uniform branch, no barriers)
        if (threadIdx.x < 8) cntA[threadIdx.x] = 0;
        return;
    }

    __shared__ float4 WD4[128];   // {Wd1[0][i], Wd1[1][i], Wd1[2][i], bd1[i]}
    __shared__ float  WD2s[128];
    __shared__ float  WGs[8][6];
    int t = threadIdx.x;
    if (t < 128){
        WD4[t] = make_float4(Wd1[t], Wd1[128+t], Wd1[256+t], bd1[t]);
        WD2s[t] = Wd2[t];
    }
    if (t < 48) WGs[t & 7][t >> 3] = Wg[t];   // Wg[k][e] flat = k*8+e
    __syncthreads();

    int base = blockIdx.x * 1024 + t;         // 4 points/thread as 2 F2 pairs
    F2 px[2], py[2], pz[2], vx[2], vy[2], vz[2], dens[2];
    int rid0[2], rid1[2];
    #pragma unroll
    for (int q=0;q<2;q++){
        int p0 = base + (2*q)*256, p1 = p0 + 256;
        px[q] = (F2){pts[3*p0],   pts[3*p1]};
        py[q] = (F2){pts[3*p0+1], pts[3*p1+1]};
        pz[q] = (F2){pts[3*p0+2], pts[3*p1+2]};
        int r0 = ray_id[p0], r1 = ray_id[p1];
        rid0[q] = r0; rid1[q] = r1;
        vx[q] = (F2){vdirs[3*r0],   vdirs[3*r1]};
        vy[q] = (F2){vdirs[3*r0+1], vdirs[3*r1+1]};
        vz[q] = (F2){vdirs[3*r0+2], vdirs[3*r1+2]};
        dens[q] = f2splat(0.f);
    }
    // ray segment boundaries
    #pragma unroll
    for (int q=0;q<2;q++){
        int p0 = base + (2*q)*256, p1 = p0 + 256;
        int prev0 = (p0 == 0) ? -1 : ray_id[p0-1];
        if (prev0 != rid0[q]) for (int r=prev0+1; r<=rid0[q]; ++r) ray_off[r] = p0;
        int prev1 = ray_id[p1-1];
        if (prev1 != rid1[q]) for (int r=prev1+1; r<=rid1[q]; ++r) ray_off[r] = p1;
        if (p1 == PTOT-1) for (int r=rid1[q]+1; r<=NRAYS; ++r) ray_off[r] = PTOT;
    }
    #pragma unroll 2
    for (int i=0;i<128;i++){
        float4 w = WD4[i]; float w2 = WD2s[i];
        #pragma unroll
        for (int q=0;q<2;q++){
            F2 h = f2fma(px[q], w.x, f2fma(py[q], w.y, f2fma(pz[q], w.z, f2splat(w.w))));
            h = __builtin_elementwise_max(h, f2splat(0.f));
            dens[q] = f2fma(h, w2, dens[q]);
        }
    }
    #pragma unroll
    for (int q=0;q<2;q++){
        float a0 = raw2alpha_f(dens[q].x);
        float a1 = raw2alpha_f(dens[q].y);
        alpha0[base + (2*q)*256]   = (a0 > THRESH) ? a0 : 0.f;
        alpha0[base + (2*q+1)*256] = (a1 > THRESH) ? a1 : 0.f;
    }
    // gate: top-2 of softmax over 8 experts, renormalized
    float m0[4], m1[4]; int i0[4], i1[4];
    #pragma unroll
    for (int j=0;j<4;j++){ m0[j]=-3.0e38f; m1[j]=-3.0e38f; i0[j]=0; i1[j]=0; }
    for (int e=0;e<8;e++){
        float w0=WGs[e][0],w1=WGs[e][1],w2=WGs[e][2],w3=WGs[e][3],w4=WGs[e][4],w5=WGs[e][5];
        #pragma unroll
        for (int q=0;q<2;q++){
            F2 l = f2fma(px[q],w0, f2fma(py[q],w1, f2fma(pz[q],w2,
                   f2fma(vx[q],w3, f2fma(vy[q],w4,
                   __builtin_elementwise_fma(vz[q], f2splat(w5), f2splat(0.f)))))));
            int j0 = 2*q, j1 = 2*q+1;
            float lx = l.x, ly = l.y;
            if (lx > m0[j0]){ m1[j0]=m0[j0]; i1[j0]=i0[j0]; m0[j0]=lx; i0[j0]=e; }
            else if (lx > m1[j0]){ m1[j0]=lx; i1[j0]=e; }
            if (ly > m0[j1]){ m1[j1]=m0[j1]; i1[j1]=i0[j1]; m0[j1]=ly; i0[j1]=e; }
            else if (ly > m1[j1]){ m1[j1]=ly; i1[j1]=e; }
        }
    }
    #pragma unroll
    for (int j=0;j<4;j++){
        float g0 = __fdividef(1.0f, 1.0f + __expf(m1[j]-m0[j]));
        g0a[base + j*256] = g0;
        eea[base + j*256] = i0[j] | (i1[j] << 8);
    }
}

// -------- kernel 2: transmittance scan + keep + DIRECT entry fill (R9, unchanged) --------
__global__ __launch_bounds__(256) void k_scanfill(
    const float* __restrict__ alpha0, const int* __restrict__ eea,
    const float* __restrict__ g0a, const int* __restrict__ ray_off,
    unsigned char* __restrict__ keep, int* __restrict__ cntA,
    int2* __restrict__ ent)
{
    __shared__ int wcs[4][8];
    __shared__ int wb[4][8];
    int t = threadIdx.x, lane = t & 63, w = t >> 6;
    unsigned long long lt = (1ull << lane) - 1ull;
    int wid = blockIdx.x*4 + w;                      // wave = ray
    int s = ray_off[wid], e = ray_off[wid+1];

    // ---- pass 1: per-ray transmittance scan -> keep + per-expert counts ----
    int c[8];
    #pragma unroll
    for (int x=0;x<8;x++) c[x]=0;
    float carry = 1.f;
    for (int ch = s; ch < e; ch += 64){
        int p = ch + lane;
        bool in = p < e;
        float a = in ? alpha0[p] : 0.f;
        int  ee = in ? eea[p] : 0;
        float incl = 1.f - a;
        #pragma unroll
        for (int d=1; d<64; d<<=1){ float tt = __shfl_up(incl, d); if (lane >= d) incl *= tt; }
        float excl = __shfl_up(incl, 1); if (lane == 0) excl = 1.f;
        float w0 = a * carry * excl;
        int k = (in && w0 > THRESH) ? 1 : 0;
        if (in) keep[p] = (unsigned char)k;
        int e0 = ee & 255, e1 = (ee >> 8) & 255;
        #pragma unroll
        for (int x=0;x<8;x++){
            unsigned long long m0 = __ballot(k && e0==x);
            unsigned long long m1 = __ballot(k && e1==x);
            c[x] += __popcll(m0) + __popcll(m1);
        }
        carry *= __shfl(incl, 63);
    }
    if (lane == 0){
        #pragma unroll
        for (int x=0;x<8;x++) wcs[w][x] = c[x];
    }
    __syncthreads();
    // ---- block-level reservation: one atomic per expert ----
    if (t < 8){
        int tot = wcs[0][t]+wcs[1][t]+wcs[2][t]+wcs[3][t];
        int b = tot ? atomicAdd(&cntA[t], tot) : 0;
        wb[0][t] = b; b += wcs[0][t];
        wb[1][t] = b; b += wcs[1][t];
        wb[2][t] = b; b += wcs[2][t];
        wb[3][t] = b;
    }
    __syncthreads();
    int cur[8];
    #pragma unroll
    for (int x=0;x<8;x++) cur[x] = x*ECAP + wb[w][x];

    // ---- pass 2: re-ballot (hot reads) + ranked scatter into fixed regions ----
    for (int ch = s; ch < e; ch += 64){
        int p = ch + lane;
        bool in = p < e;
        int  k  = in ? keep[p] : 0;
        int  ee = in ? eea[p] : 0;
        float g0 = in ? g0a[p] : 0.f;
        int e0 = ee & 255, e1 = (ee >> 8) & 255;
        #pragma unroll
        for (int x=0;x<8;x++){
            unsigned long long m0 = __ballot(k && e0==x);
            unsigned long long m1 = __ballot(k && e1==x);
            if (k && e0==x)
                ent[cur[x] + __popcll(m0 & lt)] = make_int2(p, __float_as_int(g0));
            if (k && e1==x)
                ent[cur[x] + __popcll(m0) + __popcll(m1 & lt)] =
                    make_int2(p | (1 << 30), __float_as_int(1.0f - g0));
            cur[x] += __popcll(m0) + __popcll(m1);
        }
    }
}

// ---------------- kernel 3: expert MLPs (exact R9 core — best of 9 variants) ----------
// 82.0-82.6us measured: 256 thr, 4 F2 pairs, chunk 2048, zero-dead padded-prefix grid,
// all-LDS float4 weights, vdirs re-gathered via ray_id[p] (L2-hot).
// CLOSED experiments: MFMA (99), pure s_load weights (127, R1), packed 32B entries
// (92.6, R2), pk_fma (97, R3), 16 e/t (128 R4 / 88.5 R7), 128-thr (95.9 R5),
// hybrid scalar-WA (85.6, R11). Latency-bound at ~2.6x issue floor; LDS-pipe model
// refuted (R11). This is the kernel's practical floor.
__global__ __launch_bounds__(256) void k_expert(
    const int2* __restrict__ ent, const int* __restrict__ cntA,
    const float* __restrict__ pts, const int* __restrict__ ray_id,
    const float* __restrict__ vdirs,
    const float* __restrict__ We1, const float* __restrict__ be1,
    const float* __restrict__ Wrgb, const float* __restrict__ Walpha,
    float4* __restrict__ res)
{
    // padded-prefix chunk search over per-expert counts (uniform scalar)
    int k = blockIdx.x;
    int e = -1, n = 0, base = 0;
    int acc = 0;
    #pragma unroll
    for (int i=0;i<8;i++){
        int c  = cntA[i];                    // <= ECAP by construction
        int ch = (c + 2047) >> 11;           // 2048-entry chunks this expert needs
        if (e < 0 && k < acc + ch){ e = i; n = c; base = (k - acc) << 11; }
        acc += ch;
    }
    if (e < 0) return;                        // beyond total chunk count (tail guard)

    __shared__ float4 WA[128];   // We1[e][0..3][i]
    __shared__ float4 WB[128];   // We1[e][4][i], We1[e][5][i], be1[e][i], Walpha[e][i]
    __shared__ float4 WC[128];   // Wrgb[e][i][0..2], 0
    int t = threadIdx.x;
    if (t < 128){
        const float* w = We1 + e*768;
        WA[t] = make_float4(w[t], w[128+t], w[256+t], w[384+t]);
        WB[t] = make_float4(w[512+t], w[640+t], be1[e*128+t], Walpha[e*128+t]);
        const float* wr = Wrgb + e*384 + 3*t;
        WC[t] = make_float4(wr[0], wr[1], wr[2], 0.f);
    }
    __syncthreads();
    const int2* eb = ent + (size_t)e * ECAP;

    F2 x0[4],x1[4],x2[4],x3[4],x4[4],x5[4];
    F2 ar[4],ag[4],ab[4],aa[4];
    #pragma unroll
    for (int pr=0;pr<4;pr++){
        int idx0 = base + t + (2*pr)*256, idx1 = idx0 + 256;
        int2 r0 = (idx0 < n) ? eb[idx0] : make_int2(0,0);
        int2 r1 = (idx1 < n) ? eb[idx1] : make_int2(0,0);
        int p0 = r0.x & 0x0FFFFFFF, p1 = r1.x & 0x0FFFFFFF;
        int ra = ray_id[p0], rb = ray_id[p1];
        x0[pr] = (F2){pts[3*p0],   pts[3*p1]};
        x1[pr] = (F2){pts[3*p0+1], pts[3*p1+1]};
        x2[pr] = (F2){pts[3*p0+2], pts[3*p1+2]};
        x3[pr] = (F2){vdirs[3*ra],   vdirs[3*rb]};
        x4[pr] = (F2){vdirs[3*ra+1], vdirs[3*rb+1]};
        x5[pr] = (F2){vdirs[3*ra+2], vdirs[3*rb+2]};
        ar[pr] = f2splat(0.f); ag[pr] = f2splat(0.f);
        ab[pr] = f2splat(0.f); aa[pr] = f2splat(0.f);
    }
    #pragma unroll 2
    for (int i=0;i<128;i++){
        float4 wa = WA[i], wb = WB[i], wc = WC[i];
        #pragma unroll
        for (int pr=0;pr<4;pr++){
            F2 h = f2fma(x0[pr],wa.x, f2fma(x1[pr],wa.y, f2fma(x2[pr],wa.z,
                   f2fma(x3[pr],wa.w, f2fma(x4[pr],wb.x, f2fma(x5[pr],wb.y,
                   f2splat(wb.z)))))));
            h = __builtin_elementwise_max(h, f2splat(0.f));
            ar[pr] = f2fma(h, wc.x, ar[pr]);
            ag[pr] = f2fma(h, wc.y, ag[pr]);
            ab[pr] = f2fma(h, wc.z, ab[pr]);
            aa[pr] = f2fma(h, wb.w, aa[pr]);
        }
    }
    #pragma unroll
    for (int pr=0;pr<4;pr++){
        #pragma unroll
        for (int sel=0; sel<2; sel++){
            int idx = base + t + (2*pr+sel)*256;
            if (idx < n){
                int2 rec = eb[idx];                 // reload g/pid (keeps loop VGPRs low)
                float vr = sel ? ar[pr].y : ar[pr].x;
                float vg = sel ? ag[pr].y : ag[pr].x;
                float vb = sel ? ab[pr].y : ab[pr].x;
                float va = sel ? aa[pr].y : aa[pr].x;
                float sr = __fdividef(1.0f, 1.0f + __expf(-vr));
                float sg = __fdividef(1.0f, 1.0f + __expf(-vg));
                float sb = __fdividef(1.0f, 1.0f + __expf(-vb));
                float a  = raw2alpha_f(va);
                float g  = __int_as_float(rec.y);
                int pp   = rec.x & 0x0FFFFFFF;
                int slot = ((unsigned)rec.x) >> 30;
                res[2*(size_t)pp + slot] = make_float4(g*sr, g*sg, g*sb, g*a);
            }
        }
    }
}

// ---------------- kernel 4: final per-ray composite (unchanged) ----------------
__global__ __launch_bounds__(256) void k_scan1(const float4* __restrict__ res,
                                               const unsigned char* __restrict__ keep,
                                               const int* __restrict__ ray_off,
                                               const float* __restrict__ bg,
                                               float* __restrict__ out)
{
    int wid  = (blockIdx.x*blockDim.x + threadIdx.x) >> 6;   // wave = ray
    int lane = threadIdx.x & 63;
    if (wid >= NRAYS) return;
    int s = ray_off[wid], e = ray_off[wid+1];
    float carry = 1.f;
    float accx = 0.f, accy = 0.f, accz = 0.f;
    for (int c = s; c < e; c += 64){
        int p = c + lane;
        float4 v = make_float4(0.f,0.f,0.f,0.f);
        if (p < e && keep[p]){
            float4 v0 = res[2*(size_t)p];
            float4 v1 = res[2*(size_t)p + 1];
            v = make_float4(v0.x+v1.x, v0.y+v1.y, v0.z+v1.z, v0.w+v1.w);
        }
        float a = v.w;
        float incl = 1.f - a;
        #pragma unroll
        for (int d=1; d<64; d<<=1){ float tt = __shfl_up(incl, d); if (lane >= d) incl *= tt; }
        float excl = __shfl_up(incl, 1); if (lane == 0) excl = 1.f;
        float w = a * carry * excl;
        accx = fmaf(w, v.x, accx);
        accy = fmaf(w, v.y, accy);
        accz = fmaf(w, v.z, accz);
        carry *= __shfl(incl, 63);
    }
    #pragma unroll
    for (int d=32; d; d>>=1){
        accx += __shfl_xor(accx, d);
        accy += __shfl_xor(accy, d);
        accz += __shfl_xor(accz, d);
    }
    if (lane == 0){
        out[3*wid+0] = accx + carry*bg[0];
        out[3*wid+1] = accy + carry*bg[1];
        out[3*wid+2] = accz + carry*bg[2];
    }
}

extern "C" void kernel_launch(void* const* d_in, const int* in_sizes, int n_in,
                              void* d_out, int out_size, void* d_ws, size_t ws_size,
                              hipStream_t stream)
{
    const float* pts    = (const float*)d_in[0];
    const float* vdirs  = (const float*)d_in[1];
    const float* bg     = (const float*)d_in[2];
    const float* Wd1    = (const float*)d_in[3];
    const float* bd1    = (const float*)d_in[4];
    const float* Wd2    = (const float*)d_in[5];
    const float* Wg     = (const float*)d_in[6];
    const float* We1    = (const float*)d_in[7];
    const float* be1    = (const float*)d_in[8];
    const float* Wrgb   = (const float*)d_in[9];
    const float* Walpha = (const float*)d_in[10];
    const int*   ray_id = (const int*)d_in[11];
    float* out = (float*)d_out;

    // Workspace (~97.2MB, R9-proven footprint):
    //   [keep 1MB][ray_off][cntA][A: alpha0|g0a|eea 12MB, res overlays][ent 64MB]
    char* ws = (char*)d_ws;
    size_t off = 0;
    unsigned char* keep  = (unsigned char*)(ws + off); off += (size_t)PTOT;   // 1MB
    int*   ray_off       = (int*)  (ws + off); off += 33024;                  // 8193+ ints
    int*   cntA          = (int*)  (ws + off); off += 256;
    off = (off + 255) & ~(size_t)255;
    size_t offA = off;
    float* alpha0        = (float*)(ws + offA);                                // 4MB
    float* g0a           = (float*)(ws + offA + (size_t)PTOT*4);               // 4MB
    int*   eea           = (int*)  (ws + offA + (size_t)PTOT*8);               // 4MB
    float4* res          = (float4*)(ws + offA);            // 32MB+32B, overlays A
    size_t resBytes      = ((size_t)2*PTOT + 2) * 16;
    size_t offE          = (offA + resBytes + 255) & ~(size_t)255;
    int2*  ent           = (int2*) (ws + offE);             // 8 * PTOT * 8B = 64MB

    // no memset dispatch: k_point's aux block zeroes cntA before k_scanfill runs
    k_point   <<<PTOT/1024 + 1, 256, 0, stream>>>(pts, vdirs, ray_id, Wd1, bd1, Wd2, Wg,
                                                  alpha0, g0a, eea, ray_off, cntA);
    k_scanfill<<<NRAYS/4, 256, 0, stream>>>(alpha0, eea, g0a, ray_off, keep, cntA, ent);
    // grid = max total chunks: Sum_e ceil(n_e/2048) <= 2*PTOT/2048 + 8 = 1032
    k_expert  <<<1032, 256, 0, stream>>>(ent, cntA, pts, ray_id, vdirs,
                                         We1, be1, Wrgb, Walpha, res);
    k_scan1   <<<NRAYS*64/256, 256, 0, stream>>>(res, keep, ray_off, bg, out);
}